// Round 5
// baseline (2847.702 us; speedup 1.0000x reference)
//
#include <hip/hip_runtime.h>
#include <hip/hip_bf16.h>

#define N_EVENT 10000
#define N_IOC   40000
#define N_NODES 50000
#define E_EDGES 800000
#define D_EV 768
#define D_IO 128
#define H 256
#define R 8
#define NBASES 8
#define NLAYERS 3
#define EDIM 16
#define LN_EPS 1e-5f

#define NKEY (N_NODES * R)
#define SCAN_CHUNK 2048
#define NCHUNK ((NKEY + SCAN_CHUNK - 1) / SCAN_CHUNK)
#define NC 12500                       // node-chunk for bucket+gemm
#define NCHUNKS (N_NODES / NC)         // 4 (exact)
#define KPRE (R * H)                   // 2048
#define KTOT (R * H + H)               // 2304
#define NBEV32 ((N_EVENT + 31) / 32)   // 313
#define NBIO32 (N_IOC / 32)            // 1250

typedef __hip_bfloat16 bf16;
typedef __attribute__((ext_vector_type(8))) short bf16x8;
typedef __attribute__((ext_vector_type(4))) float f32x4;

__device__ __forceinline__ float us2f(unsigned short u) {
    union { unsigned int i; float f; } x; x.i = ((unsigned int)u) << 16; return x.f;
}

// ===================== edge presort (counting sort by dst*R+rel) =====================
__global__ __launch_bounds__(256) void hist_kernel(const int* __restrict__ ei, const int* __restrict__ et,
                                                   int* __restrict__ cnt) {
    int e = blockIdx.x * 256 + threadIdx.x;
    if (e < E_EDGES) atomicAdd(&cnt[ei[E_EDGES + e] * R + et[e]], 1);
}

__global__ __launch_bounds__(256) void scan1_kernel(const int* __restrict__ cnt, int* __restrict__ offs,
                                                    int* __restrict__ bsum) {
    __shared__ int s[256];
    int t = threadIdx.x;
    long base = (long)blockIdx.x * SCAN_CHUNK + t * 8;
    int v[8]; int sum = 0;
    #pragma unroll
    for (int i = 0; i < 8; ++i) { long idx = base + i; v[i] = (idx < NKEY) ? cnt[idx] : 0; sum += v[i]; }
    s[t] = sum; __syncthreads();
    for (int off = 1; off < 256; off <<= 1) {
        int x = (t >= off) ? s[t - off] : 0;
        __syncthreads();
        s[t] += x;
        __syncthreads();
    }
    int run = s[t] - sum;
    if (t == 255) bsum[blockIdx.x] = s[255];
    #pragma unroll
    for (int i = 0; i < 8; ++i) { long idx = base + i; if (idx < NKEY) offs[idx] = run; run += v[i]; }
}

__global__ __launch_bounds__(256) void scan2_kernel(int* __restrict__ bsum) {
    __shared__ int s[256];
    int t = threadIdx.x;
    int v = (t < NCHUNK) ? bsum[t] : 0;
    s[t] = v; __syncthreads();
    for (int off = 1; off < 256; off <<= 1) {
        int x = (t >= off) ? s[t - off] : 0;
        __syncthreads();
        s[t] += x;
        __syncthreads();
    }
    if (t < NCHUNK) bsum[t] = s[t] - v;
}

__global__ __launch_bounds__(256) void scan3_kernel(int* __restrict__ offs, const int* __restrict__ bsum) {
    int i = blockIdx.x * 256 + threadIdx.x;
    if (i < NKEY) offs[i] += bsum[i / SCAN_CHUNK];
    if (i == 0) offs[NKEY] = E_EDGES;
}

__global__ __launch_bounds__(256) void cinv_kernel(const int* __restrict__ cnt, float* __restrict__ cinv) {
    int i = blockIdx.x * 256 + threadIdx.x;
    if (i < NKEY) cinv[i] = 1.0f / (float)max(cnt[i], 1);
}

__global__ __launch_bounds__(256) void sort_kernel(const int* __restrict__ ei, const int* __restrict__ et,
                                                   const float* __restrict__ ew, const int* __restrict__ offs,
                                                   int* __restrict__ cnt, int* __restrict__ ssrc,
                                                   float* __restrict__ sew) {
    int e = blockIdx.x * 256 + threadIdx.x;
    if (e >= E_EDGES) return;
    int key = ei[E_EDGES + e] * R + et[e];
    int pos = offs[key] + atomicSub(&cnt[key], 1) - 1;
    ssrc[pos] = ei[e];
    sew[pos]  = ew[e];
}

// ===================== dtype prep =====================
__global__ __launch_bounds__(256) void cvt_x_kernel(const float* __restrict__ xev, const float* __restrict__ xio,
                                                    bf16* __restrict__ xevb, bf16* __restrict__ xiob) {
    const long NEV4 = (long)N_EVENT * D_EV / 4;
    const long NTOT4 = NEV4 + (long)N_IOC * D_IO / 4;
    long i = (long)blockIdx.x * 256 + threadIdx.x;
    if (i >= NTOT4) return;
    const float4* src; ushort4* dst; long j;
    if (i < NEV4) { src = (const float4*)xev; dst = (ushort4*)xevb; j = i; }
    else          { src = (const float4*)xio; dst = (ushort4*)xiob; j = i - NEV4; }
    float4 v = src[j];
    ushort4 o;
    bf16 a0 = __float2bfloat16(v.x), a1 = __float2bfloat16(v.y);
    bf16 a2 = __float2bfloat16(v.z), a3 = __float2bfloat16(v.w);
    o.x = *(unsigned short*)&a0; o.y = *(unsigned short*)&a1;
    o.z = *(unsigned short*)&a2; o.w = *(unsigned short*)&a3;
    dst[j] = o;
}

__global__ __launch_bounds__(256) void cvt_w_kernel(const float* __restrict__ wev, const float* __restrict__ wio,
                                                    bf16* __restrict__ wevT, bf16* __restrict__ wioT) {
    int n = blockIdx.x;
    for (int k = threadIdx.x; k < D_EV; k += 256)
        wevT[(size_t)n * D_EV + k] = __float2bfloat16(wev[(size_t)k * H + n]);
    for (int k = threadIdx.x; k < D_IO; k += 256)
        wioT[(size_t)n * D_IO + k] = __float2bfloat16(wio[(size_t)k * H + n]);
}

__global__ __launch_bounds__(256) void build_Bt_kernel(
    const float* __restrict__ bases, const float* __restrict__ comp, const float* __restrict__ root,
    bf16* __restrict__ Bt3) {
    int gb = blockIdx.x;
    int l = gb / KTOT, krow = gb % KTOT;
    int n = threadIdx.x;
    float v;
    if (krow < KPRE) {
        int r = krow >> 8, kk = krow & 255;
        v = 0.0f;
        const float* bs = bases + (size_t)l * NBASES * H * H + (size_t)kk * H + n;
        const float* cp = comp + (l * R + r) * NBASES;
        #pragma unroll
        for (int b = 0; b < NBASES; ++b) v += cp[b] * bs[(size_t)b * H * H];
    } else {
        int kk = krow - KPRE;
        v = root[((size_t)l * H + kk) * H + n];
    }
    Bt3[(size_t)l * H * KTOT + (size_t)n * KTOT + krow] = __float2bfloat16(v);
}

// ===================== edge-feature path =====================
__global__ __launch_bounds__(256) void edge_table_kernel(
    const float* __restrict__ emb, const float* __restrict__ mlp_w,
    const float* __restrict__ mlp_b, float* __restrict__ ctab, float* __restrict__ wlast) {
    int r = blockIdx.x, j = threadIdx.x;
    float acc = mlp_b[j];
    #pragma unroll
    for (int k = 0; k < EDIM; ++k) acc += emb[r * EDIM + k] * mlp_w[k * H + j];
    ctab[r * H + j] = acc;
    if (r == 0) wlast[j] = mlp_w[EDIM * H + j];
}

__global__ __launch_bounds__(256) void enh_bucket_kernel(
    const int* __restrict__ offs, const float* __restrict__ sew,
    const float* __restrict__ ctab, const float* __restrict__ wlast,
    bf16* __restrict__ enh) {
    __shared__ float ct[R * H];
    __shared__ float wl[H];
    for (int i = threadIdx.x; i < R * H; i += 256) ct[i] = ctab[i];
    for (int i = threadIdx.x; i < H; i += 256) wl[i] = wlast[i];
    __syncthreads();
    int w = threadIdx.x >> 6, lane = threadIdx.x & 63;
    int d = blockIdx.x * 4 + w;
    float acc[4] = {0.f, 0.f, 0.f, 0.f};
    int deg = offs[d * R + R] - offs[d * R];
    for (int r = 0; r < R; ++r) {
        int a = offs[d * R + r], b = offs[d * R + r + 1];
        for (int j = a; j < b; ++j) {
            float wt = sew[j];
            #pragma unroll
            for (int i = 0; i < 4; ++i) {
                int c = lane * 4 + i;
                acc[i] += fmaxf(ct[r * H + c] + wt * wl[c], 0.0f);
            }
        }
    }
    float inv = 1.0f / fmaxf((float)deg, 1.0f);
    unsigned short o[4];
    #pragma unroll
    for (int i = 0; i < 4; ++i) { bf16 hv = __float2bfloat16(acc[i] * inv); o[i] = *(unsigned short*)&hv; }
    *(ushort4*)(enh + (size_t)d * H + lane * 4) = *(ushort4*)o;
}

// ===================== bucket sums =====================
__global__ __launch_bounds__(256) void bucket_msg_kernel(
    const int* __restrict__ offs, const int* __restrict__ ssrc,
    const bf16* __restrict__ hbR, const float* __restrict__ cinv,
    bf16* __restrict__ pre, int c0) {
    int w = threadIdx.x >> 6, lane = threadIdx.x & 63;
    int d = c0 + blockIdx.x;
    size_t prow = (size_t)blockIdx.x * KPRE;
    #pragma unroll
    for (int rr = 0; rr < 2; ++rr) {
        int r = w * 2 + rr;
        float acc[4] = {0.f, 0.f, 0.f, 0.f};
        int a = offs[d * R + r], b = offs[d * R + r + 1];
        for (int j = a; j < b; ++j) {
            int s = ssrc[j];
            ushort4 u = *(const ushort4*)(hbR + (size_t)s * H + lane * 4);
            acc[0] += us2f(u.x); acc[1] += us2f(u.y); acc[2] += us2f(u.z); acc[3] += us2f(u.w);
        }
        float sc = cinv[d * R + r];
        unsigned short o[4];
        #pragma unroll
        for (int i = 0; i < 4; ++i) { bf16 hv = __float2bfloat16(acc[i] * sc); o[i] = *(unsigned short*)&hv; }
        *(ushort4*)(pre + prow + r * H + lane * 4) = *(ushort4*)o;
    }
}

// ===================== barrier-free layer GEMM + fused LN/ReLU/residual =====================
// One wave per block; computes 32 rows x 256 cols. B fragments straight from L2 (Bt is 1.15 MB).
__global__ __launch_bounds__(64) void gemm2_kernel(
    const bf16* __restrict__ pre, const bf16* __restrict__ hbR,
    const bf16* __restrict__ Bt, const bf16* __restrict__ enh,
    const float* __restrict__ bias, const float* __restrict__ gamma, const float* __restrict__ beta,
    bf16* __restrict__ hbW, int c0) {
    int lane = threadIdx.x;
    int quad = lane >> 4, m = lane & 15;
    int row0 = blockIdx.x * 32;
    f32x4 acc0[16], acc1[16];
    #pragma unroll
    for (int c = 0; c < 16; ++c) {
        acc0[c][0]=0.f; acc0[c][1]=0.f; acc0[c][2]=0.f; acc0[c][3]=0.f;
        acc1[c][0]=0.f; acc1[c][1]=0.f; acc1[c][2]=0.f; acc1[c][3]=0.f;
    }
    int rA0 = row0 + m;      if (rA0 >= NC) rA0 = NC - 1;
    int rA1 = row0 + 16 + m; if (rA1 >= NC) rA1 = NC - 1;
    const bf16* A0p = pre + (size_t)rA0 * KPRE;
    const bf16* A1p = pre + (size_t)rA1 * KPRE;
    const bf16* A0h = hbR + (size_t)(c0 + rA0) * H;
    const bf16* A1h = hbR + (size_t)(c0 + rA1) * H;
    const bf16* Bbase = Bt + (size_t)m * KTOT;

    #pragma unroll 2
    for (int kc = 0; kc < KTOT / 32; ++kc) {
        int k0 = kc * 32;
        bf16x8 a0, a1;
        if (k0 < KPRE) {
            a0 = *(const bf16x8*)(A0p + k0 + quad * 8);
            a1 = *(const bf16x8*)(A1p + k0 + quad * 8);
        } else {
            a0 = *(const bf16x8*)(A0h + (k0 - KPRE) + quad * 8);
            a1 = *(const bf16x8*)(A1h + (k0 - KPRE) + quad * 8);
        }
        const bf16* bp = Bbase + k0 + quad * 8;
        #pragma unroll
        for (int c = 0; c < 16; ++c) {
            bf16x8 b = *(const bf16x8*)(bp + (size_t)c * 16 * KTOT);
            acc0[c] = __builtin_amdgcn_mfma_f32_16x16x32_bf16(a0, b, acc0[c], 0, 0, 0);
            acc1[c] = __builtin_amdgcn_mfma_f32_16x16x32_bf16(a1, b, acc1[c], 0, 0, 0);
        }
    }

    // epilogue: v = acc + bias + 0.1*enh ; LN over 256 cols (shfl across m-lanes) ; relu ; residual
    float bv[16], gv[16], tv[16];
    #pragma unroll
    for (int c = 0; c < 16; ++c) {
        int col = c * 16 + m;
        bv[c] = bias[col]; gv[c] = gamma[col]; tv[c] = beta[col];
    }
    float s0[4]={0,0,0,0}, q0[4]={0,0,0,0}, s1[4]={0,0,0,0}, q1[4]={0,0,0,0};
    #pragma unroll
    for (int c = 0; c < 16; ++c) {
        #pragma unroll
        for (int i = 0; i < 4; ++i) {
            int r0 = row0 + quad * 4 + i;        int rr0 = (r0 < NC) ? r0 : (NC - 1);
            int r1 = row0 + 16 + quad * 4 + i;   int rr1 = (r1 < NC) ? r1 : (NC - 1);
            int col = c * 16 + m;
            float e0 = us2f(*(const unsigned short*)(enh + (size_t)(c0 + rr0) * H + col));
            float e1 = us2f(*(const unsigned short*)(enh + (size_t)(c0 + rr1) * H + col));
            float v0 = acc0[c][i] + bv[c] + 0.1f * e0;
            float v1 = acc1[c][i] + bv[c] + 0.1f * e1;
            acc0[c][i] = v0; acc1[c][i] = v1;
            s0[i] += v0; q0[i] += v0 * v0;
            s1[i] += v1; q1[i] += v1 * v1;
        }
    }
    #pragma unroll
    for (int msk = 1; msk < 16; msk <<= 1) {
        #pragma unroll
        for (int i = 0; i < 4; ++i) {
            s0[i] += __shfl_xor(s0[i], msk); q0[i] += __shfl_xor(q0[i], msk);
            s1[i] += __shfl_xor(s1[i], msk); q1[i] += __shfl_xor(q1[i], msk);
        }
    }
    float mu0[4], rs0[4], mu1[4], rs1[4];
    #pragma unroll
    for (int i = 0; i < 4; ++i) {
        mu0[i] = s0[i] * (1.0f / H);
        rs0[i] = rsqrtf(q0[i] * (1.0f / H) - mu0[i] * mu0[i] + LN_EPS);
        mu1[i] = s1[i] * (1.0f / H);
        rs1[i] = rsqrtf(q1[i] * (1.0f / H) - mu1[i] * mu1[i] + LN_EPS);
    }
    #pragma unroll
    for (int c = 0; c < 16; ++c) {
        #pragma unroll
        for (int i = 0; i < 4; ++i) {
            int col = c * 16 + m;
            int r0 = row0 + quad * 4 + i;
            if (r0 < NC) {
                size_t idx = (size_t)(c0 + r0) * H + col;
                float y = (acc0[c][i] - mu0[i]) * rs0[i] * gv[c] + tv[c];
                float hn = us2f(*(const unsigned short*)(hbR + idx)) + fmaxf(y, 0.0f);
                hbW[idx] = __float2bfloat16(hn);
            }
            int r1 = row0 + 16 + quad * 4 + i;
            if (r1 < NC) {
                size_t idx = (size_t)(c0 + r1) * H + col;
                float y = (acc1[c][i] - mu1[i]) * rs1[i] * gv[c] + tv[c];
                float hn = us2f(*(const unsigned short*)(hbR + idx)) + fmaxf(y, 0.0f);
                hbW[idx] = __float2bfloat16(hn);
            }
        }
    }
}

// ===================== barrier-free input projection GEMM + fused LN/ReLU =====================
__global__ __launch_bounds__(64) void proj2_kernel(
    const bf16* __restrict__ xevb, const bf16* __restrict__ xiob,
    const bf16* __restrict__ wevT, const bf16* __restrict__ wioT,
    const float* __restrict__ bev, const float* __restrict__ gev, const float* __restrict__ betev,
    const float* __restrict__ bio, const float* __restrict__ gio, const float* __restrict__ betio,
    bf16* __restrict__ hbW) {
    int lane = threadIdx.x;
    int quad = lane >> 4, m = lane & 15;
    int blk = blockIdx.x;
    const bf16 *X, *WT; const float *bb, *gg, *be;
    int K, node0, x0, nvalid;
    if (blk < NBEV32) {
        X = xevb; WT = wevT; K = D_EV; x0 = blk * 32; node0 = x0;
        bb = bev; gg = gev; be = betev;
        nvalid = (N_EVENT - x0 < 32) ? (N_EVENT - x0) : 32;
    } else {
        int b2 = blk - NBEV32;
        X = xiob; WT = wioT; K = D_IO; x0 = b2 * 32; node0 = N_EVENT + x0;
        bb = bio; gg = gio; be = betio;
        nvalid = 32;
    }
    f32x4 acc0[16], acc1[16];
    #pragma unroll
    for (int c = 0; c < 16; ++c) {
        acc0[c][0]=0.f; acc0[c][1]=0.f; acc0[c][2]=0.f; acc0[c][3]=0.f;
        acc1[c][0]=0.f; acc1[c][1]=0.f; acc1[c][2]=0.f; acc1[c][3]=0.f;
    }
    int rA0 = m;      if (rA0 >= nvalid) rA0 = nvalid - 1;
    int rA1 = 16 + m; if (rA1 >= nvalid) rA1 = nvalid - 1;
    const bf16* A0 = X + (size_t)(x0 + rA0) * K;
    const bf16* A1 = X + (size_t)(x0 + rA1) * K;
    const bf16* Bbase = WT + (size_t)m * K;

    for (int kc = 0; kc < K / 32; ++kc) {
        int k0 = kc * 32;
        bf16x8 a0 = *(const bf16x8*)(A0 + k0 + quad * 8);
        bf16x8 a1 = *(const bf16x8*)(A1 + k0 + quad * 8);
        const bf16* bp = Bbase + k0 + quad * 8;
        #pragma unroll
        for (int c = 0; c < 16; ++c) {
            bf16x8 b = *(const bf16x8*)(bp + (size_t)c * 16 * K);
            acc0[c] = __builtin_amdgcn_mfma_f32_16x16x32_bf16(a0, b, acc0[c], 0, 0, 0);
            acc1[c] = __builtin_amdgcn_mfma_f32_16x16x32_bf16(a1, b, acc1[c], 0, 0, 0);
        }
    }

    float bv[16], gv[16], tv[16];
    #pragma unroll
    for (int c = 0; c < 16; ++c) {
        int col = c * 16 + m;
        bv[c] = bb[col]; gv[c] = gg[col]; tv[c] = be[col];
    }
    float s0[4]={0,0,0,0}, q0[4]={0,0,0,0}, s1[4]={0,0,0,0}, q1[4]={0,0,0,0};
    #pragma unroll
    for (int c = 0; c < 16; ++c) {
        #pragma unroll
        for (int i = 0; i < 4; ++i) {
            float v0 = acc0[c][i] + bv[c];
            float v1 = acc1[c][i] + bv[c];
            acc0[c][i] = v0; acc1[c][i] = v1;
            s0[i] += v0; q0[i] += v0 * v0;
            s1[i] += v1; q1[i] += v1 * v1;
        }
    }
    #pragma unroll
    for (int msk = 1; msk < 16; msk <<= 1) {
        #pragma unroll
        for (int i = 0; i < 4; ++i) {
            s0[i] += __shfl_xor(s0[i], msk); q0[i] += __shfl_xor(q0[i], msk);
            s1[i] += __shfl_xor(s1[i], msk); q1[i] += __shfl_xor(q1[i], msk);
        }
    }
    float mu0[4], rs0[4], mu1[4], rs1[4];
    #pragma unroll
    for (int i = 0; i < 4; ++i) {
        mu0[i] = s0[i] * (1.0f / H);
        rs0[i] = rsqrtf(q0[i] * (1.0f / H) - mu0[i] * mu0[i] + LN_EPS);
        mu1[i] = s1[i] * (1.0f / H);
        rs1[i] = rsqrtf(q1[i] * (1.0f / H) - mu1[i] * mu1[i] + LN_EPS);
    }
    #pragma unroll
    for (int c = 0; c < 16; ++c) {
        #pragma unroll
        for (int i = 0; i < 4; ++i) {
            int col = c * 16 + m;
            int r0 = quad * 4 + i;
            if (r0 < nvalid) {
                float y = (acc0[c][i] - mu0[i]) * rs0[i] * gv[c] + tv[c];
                hbW[(size_t)(node0 + r0) * H + col] = __float2bfloat16(fmaxf(y, 0.0f));
            }
            int r1 = 16 + quad * 4 + i;
            if (r1 < nvalid) {
                float y = (acc1[c][i] - mu1[i]) * rs1[i] * gv[c] + tv[c];
                hbW[(size_t)(node0 + r1) * H + col] = __float2bfloat16(fmaxf(y, 0.0f));
            }
        }
    }
}

__global__ __launch_bounds__(256) void out_kernel(const bf16* __restrict__ hb, float* __restrict__ out) {
    size_t i = (size_t)blockIdx.x * 256 + threadIdx.x;
    if (i < (size_t)N_EVENT * H) out[i] = us2f(*(const unsigned short*)(hb + i));
}

extern "C" void kernel_launch(void* const* d_in, const int* in_sizes, int n_in,
                              void* d_out, int out_size, void* d_ws, size_t ws_size,
                              hipStream_t stream) {
    const float* xev   = (const float*)d_in[0];
    const float* xio   = (const float*)d_in[1];
    const int*   ei    = (const int*)d_in[2];
    const int*   et    = (const int*)d_in[3];
    const float* ew    = (const float*)d_in[4];
    const float* wev   = (const float*)d_in[5];
    const float* bev   = (const float*)d_in[6];
    const float* gev   = (const float*)d_in[7];
    const float* betev = (const float*)d_in[8];
    const float* wio   = (const float*)d_in[9];
    const float* bio   = (const float*)d_in[10];
    const float* gio   = (const float*)d_in[11];
    const float* betio = (const float*)d_in[12];
    const float* emb   = (const float*)d_in[13];
    const float* mlp_w = (const float*)d_in[14];
    const float* mlp_b = (const float*)d_in[15];
    const float* bases = (const float*)d_in[16];
    const float* comp  = (const float*)d_in[17];
    const float* root  = (const float*)d_in[18];
    const float* bias  = (const float*)d_in[19];
    const float* gamma = (const float*)d_in[20];
    const float* beta  = (const float*)d_in[21];

    char* base = (char*)d_ws;
    size_t o = 0;
    auto alloc = [&](size_t bytes) { char* p = base + o; o = (o + bytes + 255) & ~(size_t)255; return p; };
    bf16*  hbA  = (bf16*) alloc((size_t)N_NODES * H * 2);          // 25.6 MB
    bf16*  hbB  = (bf16*) alloc((size_t)N_NODES * H * 2);          // 25.6 MB
    bf16*  enh  = (bf16*) alloc((size_t)N_NODES * H * 2);          // 25.6 MB
    char*  un   = alloc((size_t)NC * KPRE * 2);                    // 51.2 MB union
    bf16*  pre  = (bf16*)un;
    bf16*  xevb = (bf16*)un;
    bf16*  xiob = (bf16*)(un + (size_t)N_EVENT * D_EV * 2);
    bf16*  wevT = (bf16*) alloc((size_t)H * D_EV * 2);
    bf16*  wioT = (bf16*) alloc((size_t)H * D_IO * 2);
    bf16*  Bt3  = (bf16*) alloc((size_t)NLAYERS * H * KTOT * 2);   // 3.5 MB
    float* ctab = (float*)alloc(R * H * 4);
    float* wlast= (float*)alloc(H * 4);
    float* cinv = (float*)alloc((size_t)NKEY * 4);
    int*   bsum = (int*)  alloc(256 * 4);
    int*   cnt  = (int*)  alloc((size_t)NKEY * 4);
    int*   offs = (int*)  alloc((size_t)(NKEY + 4) * 4);
    int*   ssrc = (int*)  alloc((size_t)E_EDGES * 4);
    float* sew  = (float*)alloc((size_t)E_EDGES * 4);
    // ~143 MB total

    hipMemsetAsync(cnt, 0, (size_t)NKEY * sizeof(int), stream);

    // edge presort
    hist_kernel<<<(E_EDGES + 255) / 256, 256, 0, stream>>>(ei, et, cnt);
    scan1_kernel<<<NCHUNK, 256, 0, stream>>>(cnt, offs, bsum);
    scan2_kernel<<<1, 256, 0, stream>>>(bsum);
    scan3_kernel<<<(NKEY + 255) / 256, 256, 0, stream>>>(offs, bsum);
    cinv_kernel<<<(NKEY + 255) / 256, 256, 0, stream>>>(cnt, cinv);
    sort_kernel<<<(E_EDGES + 255) / 256, 256, 0, stream>>>(ei, et, ew, offs, cnt, ssrc, sew);

    // dtype prep
    cvt_x_kernel<<<12500, 256, 0, stream>>>(xev, xio, xevb, xiob);
    cvt_w_kernel<<<H, 256, 0, stream>>>(wev, wio, wevT, wioT);
    build_Bt_kernel<<<NLAYERS * KTOT, 256, 0, stream>>>(bases, comp, root, Bt3);

    // node features + edge-feature means
    proj2_kernel<<<NBEV32 + NBIO32, 64, 0, stream>>>(
        xevb, xiob, wevT, wioT, bev, gev, betev, bio, gio, betio, hbA);
    edge_table_kernel<<<R, 256, 0, stream>>>(emb, mlp_w, mlp_b, ctab, wlast);
    enh_bucket_kernel<<<N_NODES / 4, 256, 0, stream>>>(offs, sew, ctab, wlast, enh);

    for (int l = 0; l < NLAYERS; ++l) {
        bf16* hbR = (l & 1) ? hbB : hbA;
        bf16* hbW = (l & 1) ? hbA : hbB;
        const bf16* Bt = Bt3 + (size_t)l * H * KTOT;
        for (int c = 0; c < NCHUNKS; ++c) {
            int c0 = c * NC;
            bucket_msg_kernel<<<NC, 256, 0, stream>>>(offs, ssrc, hbR, cinv, pre, c0);
            gemm2_kernel<<<(NC + 31) / 32, 64, 0, stream>>>(
                pre, hbR, Bt, enh, bias + l * H, gamma + l * H, beta + l * H, hbW, c0);
        }
    }

    out_kernel<<<((size_t)N_EVENT * H + 255) / 256, 256, 0, stream>>>(hbB, (float*)d_out);
}

// Round 6
// 1961.404 us; speedup vs baseline: 1.4519x; 1.4519x over previous
//
#include <hip/hip_runtime.h>
#include <hip/hip_bf16.h>

#define N_EVENT 10000
#define N_IOC   40000
#define N_NODES 50000
#define E_EDGES 800000
#define D_EV 768
#define D_IO 128
#define H 256
#define R 8
#define NBASES 8
#define NLAYERS 3
#define EDIM 16
#define LN_EPS 1e-5f

#define NKEY (N_NODES * R)
#define SCAN_CHUNK 2048
#define NCHUNK ((NKEY + SCAN_CHUNK - 1) / SCAN_CHUNK)
#define NC 25000                       // node-chunk for bucket+gemm (pre = 102.4 MB)
#define NCHUNKS (N_NODES / NC)         // 2 (exact)
#define KPRE (R * H)                   // 2048
#define KTOT (R * H + H)               // 2304
#define NBEV32 ((N_EVENT + 31) / 32)   // 313
#define NBIO32 (N_IOC / 32)            // 1250

typedef __hip_bfloat16 bf16;
typedef __attribute__((ext_vector_type(8))) short bf16x8;
typedef __attribute__((ext_vector_type(4))) float f32x4;

__device__ __forceinline__ float us2f(unsigned short u) {
    union { unsigned int i; float f; } x; x.i = ((unsigned int)u) << 16; return x.f;
}

// ===================== edge presort (counting sort by dst*R+rel) =====================
__global__ __launch_bounds__(256) void hist_kernel(const int* __restrict__ ei, const int* __restrict__ et,
                                                   int* __restrict__ cnt) {
    int e = blockIdx.x * 256 + threadIdx.x;
    if (e < E_EDGES) atomicAdd(&cnt[ei[E_EDGES + e] * R + et[e]], 1);
}

__global__ __launch_bounds__(256) void scan1_kernel(const int* __restrict__ cnt, int* __restrict__ offs,
                                                    int* __restrict__ bsum) {
    __shared__ int s[256];
    int t = threadIdx.x;
    long base = (long)blockIdx.x * SCAN_CHUNK + t * 8;
    int v[8]; int sum = 0;
    #pragma unroll
    for (int i = 0; i < 8; ++i) { long idx = base + i; v[i] = (idx < NKEY) ? cnt[idx] : 0; sum += v[i]; }
    s[t] = sum; __syncthreads();
    for (int off = 1; off < 256; off <<= 1) {
        int x = (t >= off) ? s[t - off] : 0;
        __syncthreads();
        s[t] += x;
        __syncthreads();
    }
    int run = s[t] - sum;
    if (t == 255) bsum[blockIdx.x] = s[255];
    #pragma unroll
    for (int i = 0; i < 8; ++i) { long idx = base + i; if (idx < NKEY) offs[idx] = run; run += v[i]; }
}

__global__ __launch_bounds__(256) void scan2_kernel(int* __restrict__ bsum) {
    __shared__ int s[256];
    int t = threadIdx.x;
    int v = (t < NCHUNK) ? bsum[t] : 0;
    s[t] = v; __syncthreads();
    for (int off = 1; off < 256; off <<= 1) {
        int x = (t >= off) ? s[t - off] : 0;
        __syncthreads();
        s[t] += x;
        __syncthreads();
    }
    if (t < NCHUNK) bsum[t] = s[t] - v;
}

__global__ __launch_bounds__(256) void scan3_kernel(int* __restrict__ offs, const int* __restrict__ bsum) {
    int i = blockIdx.x * 256 + threadIdx.x;
    if (i < NKEY) offs[i] += bsum[i / SCAN_CHUNK];
    if (i == 0) offs[NKEY] = E_EDGES;
}

__global__ __launch_bounds__(256) void cinv_kernel(const int* __restrict__ cnt, float* __restrict__ cinv) {
    int i = blockIdx.x * 256 + threadIdx.x;
    if (i < NKEY) cinv[i] = 1.0f / (float)max(cnt[i], 1);
}

__global__ __launch_bounds__(256) void sort_kernel(const int* __restrict__ ei, const int* __restrict__ et,
                                                   const float* __restrict__ ew, const int* __restrict__ offs,
                                                   int* __restrict__ cnt, int* __restrict__ ssrc,
                                                   float* __restrict__ sew) {
    int e = blockIdx.x * 256 + threadIdx.x;
    if (e >= E_EDGES) return;
    int key = ei[E_EDGES + e] * R + et[e];
    int pos = offs[key] + atomicSub(&cnt[key], 1) - 1;
    ssrc[pos] = ei[e];
    sew[pos]  = ew[e];
}

// ===================== dtype prep =====================
__global__ __launch_bounds__(256) void cvt_x_kernel(const float* __restrict__ xev, const float* __restrict__ xio,
                                                    bf16* __restrict__ xevb, bf16* __restrict__ xiob) {
    const long NEV4 = (long)N_EVENT * D_EV / 4;
    const long NTOT4 = NEV4 + (long)N_IOC * D_IO / 4;
    long i = (long)blockIdx.x * 256 + threadIdx.x;
    if (i >= NTOT4) return;
    const float4* src; ushort4* dst; long j;
    if (i < NEV4) { src = (const float4*)xev; dst = (ushort4*)xevb; j = i; }
    else          { src = (const float4*)xio; dst = (ushort4*)xiob; j = i - NEV4; }
    float4 v = src[j];
    ushort4 o;
    bf16 a0 = __float2bfloat16(v.x), a1 = __float2bfloat16(v.y);
    bf16 a2 = __float2bfloat16(v.z), a3 = __float2bfloat16(v.w);
    o.x = *(unsigned short*)&a0; o.y = *(unsigned short*)&a1;
    o.z = *(unsigned short*)&a2; o.w = *(unsigned short*)&a3;
    dst[j] = o;
}

__global__ __launch_bounds__(256) void cvt_w_kernel(const float* __restrict__ wev, const float* __restrict__ wio,
                                                    bf16* __restrict__ wevT, bf16* __restrict__ wioT) {
    int n = blockIdx.x;
    for (int k = threadIdx.x; k < D_EV; k += 256)
        wevT[(size_t)n * D_EV + k] = __float2bfloat16(wev[(size_t)k * H + n]);
    for (int k = threadIdx.x; k < D_IO; k += 256)
        wioT[(size_t)n * D_IO + k] = __float2bfloat16(wio[(size_t)k * H + n]);
}

__global__ __launch_bounds__(256) void build_Bt_kernel(
    const float* __restrict__ bases, const float* __restrict__ comp, const float* __restrict__ root,
    bf16* __restrict__ Bt3) {
    int gb = blockIdx.x;
    int l = gb / KTOT, krow = gb % KTOT;
    int n = threadIdx.x;
    float v;
    if (krow < KPRE) {
        int r = krow >> 8, kk = krow & 255;
        v = 0.0f;
        const float* bs = bases + (size_t)l * NBASES * H * H + (size_t)kk * H + n;
        const float* cp = comp + (l * R + r) * NBASES;
        #pragma unroll
        for (int b = 0; b < NBASES; ++b) v += cp[b] * bs[(size_t)b * H * H];
    } else {
        int kk = krow - KPRE;
        v = root[((size_t)l * H + kk) * H + n];
    }
    Bt3[(size_t)l * H * KTOT + (size_t)n * KTOT + krow] = __float2bfloat16(v);
}

// ===================== edge-feature path =====================
__global__ __launch_bounds__(256) void edge_table_kernel(
    const float* __restrict__ emb, const float* __restrict__ mlp_w,
    const float* __restrict__ mlp_b, float* __restrict__ ctab, float* __restrict__ wlast) {
    int r = blockIdx.x, j = threadIdx.x;
    float acc = mlp_b[j];
    #pragma unroll
    for (int k = 0; k < EDIM; ++k) acc += emb[r * EDIM + k] * mlp_w[k * H + j];
    ctab[r * H + j] = acc;
    if (r == 0) wlast[j] = mlp_w[EDIM * H + j];
}

__global__ __launch_bounds__(256) void enh_bucket_kernel(
    const int* __restrict__ offs, const float* __restrict__ sew,
    const float* __restrict__ ctab, const float* __restrict__ wlast,
    bf16* __restrict__ enh) {
    __shared__ float ct[R * H];
    __shared__ float wl[H];
    for (int i = threadIdx.x; i < R * H; i += 256) ct[i] = ctab[i];
    for (int i = threadIdx.x; i < H; i += 256) wl[i] = wlast[i];
    __syncthreads();
    int w = threadIdx.x >> 6, lane = threadIdx.x & 63;
    int d = blockIdx.x * 4 + w;
    float acc[4] = {0.f, 0.f, 0.f, 0.f};
    int deg = offs[d * R + R] - offs[d * R];
    for (int r = 0; r < R; ++r) {
        int a = offs[d * R + r], b = offs[d * R + r + 1];
        for (int j = a; j < b; ++j) {
            float wt = sew[j];
            #pragma unroll
            for (int i = 0; i < 4; ++i) {
                int c = lane * 4 + i;
                acc[i] += fmaxf(ct[r * H + c] + wt * wl[c], 0.0f);
            }
        }
    }
    float inv = 1.0f / fmaxf((float)deg, 1.0f);
    unsigned short o[4];
    #pragma unroll
    for (int i = 0; i < 4; ++i) { bf16 hv = __float2bfloat16(acc[i] * inv); o[i] = *(unsigned short*)&hv; }
    *(ushort4*)(enh + (size_t)d * H + lane * 4) = *(ushort4*)o;
}

// ===================== bucket sums =====================
__global__ __launch_bounds__(256) void bucket_msg_kernel(
    const int* __restrict__ offs, const int* __restrict__ ssrc,
    const bf16* __restrict__ hbR, const float* __restrict__ cinv,
    bf16* __restrict__ pre, int c0) {
    int w = threadIdx.x >> 6, lane = threadIdx.x & 63;
    int d = c0 + blockIdx.x;
    size_t prow = (size_t)blockIdx.x * KPRE;
    #pragma unroll
    for (int rr = 0; rr < 2; ++rr) {
        int r = w * 2 + rr;
        float acc[4] = {0.f, 0.f, 0.f, 0.f};
        int a = offs[d * R + r], b = offs[d * R + r + 1];
        for (int j = a; j < b; ++j) {
            int s = ssrc[j];
            ushort4 u = *(const ushort4*)(hbR + (size_t)s * H + lane * 4);
            acc[0] += us2f(u.x); acc[1] += us2f(u.y); acc[2] += us2f(u.z); acc[3] += us2f(u.w);
        }
        float sc = cinv[d * R + r];
        unsigned short o[4];
        #pragma unroll
        for (int i = 0; i < 4; ++i) { bf16 hv = __float2bfloat16(acc[i] * sc); o[i] = *(unsigned short*)&hv; }
        *(ushort4*)(pre + prow + r * H + lane * 4) = *(ushort4*)o;
    }
}

// ===================== col-split barrier-free layer GEMM + fused LN/ReLU/residual ========
// Block = 4 waves over rows [row0,row0+32); wave w computes cols [64w,64w+64).
// K-loop has NO barriers (B straight from L2); one LDS reduction for LN in the epilogue.
__global__ __launch_bounds__(256) void gemm3_kernel(
    const bf16* __restrict__ pre, const bf16* __restrict__ hbR,
    const bf16* __restrict__ Bt, const bf16* __restrict__ enh,
    const float* __restrict__ bias, const float* __restrict__ gamma, const float* __restrict__ beta,
    bf16* __restrict__ hbW, int c0) {
    int t = threadIdx.x, w = t >> 6, lane = t & 63;
    int quad = lane >> 4, m = lane & 15;
    int row0 = blockIdx.x * 32;
    f32x4 acc0[4], acc1[4];
    #pragma unroll
    for (int c = 0; c < 4; ++c) {
        acc0[c][0]=0.f; acc0[c][1]=0.f; acc0[c][2]=0.f; acc0[c][3]=0.f;
        acc1[c][0]=0.f; acc1[c][1]=0.f; acc1[c][2]=0.f; acc1[c][3]=0.f;
    }
    int rA0 = row0 + m;      if (rA0 >= NC) rA0 = NC - 1;
    int rA1 = row0 + 16 + m; if (rA1 >= NC) rA1 = NC - 1;
    const bf16* A0p = pre + (size_t)rA0 * KPRE;
    const bf16* A1p = pre + (size_t)rA1 * KPRE;
    const bf16* A0h = hbR + (size_t)(c0 + rA0) * H;
    const bf16* A1h = hbR + (size_t)(c0 + rA1) * H;
    const bf16* Bbase = Bt + (size_t)(w * 64 + m) * KTOT;   // + c*16*KTOT per col-tile

    for (int kc = 0; kc < KTOT / 32; ++kc) {
        int k0 = kc * 32;
        bf16x8 a0, a1;
        if (k0 < KPRE) {
            a0 = *(const bf16x8*)(A0p + k0 + quad * 8);
            a1 = *(const bf16x8*)(A1p + k0 + quad * 8);
        } else {
            a0 = *(const bf16x8*)(A0h + (k0 - KPRE) + quad * 8);
            a1 = *(const bf16x8*)(A1h + (k0 - KPRE) + quad * 8);
        }
        const bf16* bp = Bbase + k0 + quad * 8;
        #pragma unroll
        for (int c = 0; c < 4; ++c) {
            bf16x8 b = *(const bf16x8*)(bp + (size_t)c * 16 * KTOT);
            acc0[c] = __builtin_amdgcn_mfma_f32_16x16x32_bf16(a0, b, acc0[c], 0, 0, 0);
            acc1[c] = __builtin_amdgcn_mfma_f32_16x16x32_bf16(a1, b, acc1[c], 0, 0, 0);
        }
    }

    // epilogue: v = acc + bias + 0.1*enh ; LN over 256 cols (shfl over m, LDS over waves)
    float bv[4], gv[4], tv[4];
    #pragma unroll
    for (int c = 0; c < 4; ++c) {
        int col = w * 64 + c * 16 + m;
        bv[c] = bias[col]; gv[c] = gamma[col]; tv[c] = beta[col];
    }
    float s0[4]={0,0,0,0}, q0[4]={0,0,0,0}, s1[4]={0,0,0,0}, q1[4]={0,0,0,0};
    #pragma unroll
    for (int c = 0; c < 4; ++c) {
        #pragma unroll
        for (int i = 0; i < 4; ++i) {
            int r0 = row0 + quad * 4 + i;        int rr0 = (r0 < NC) ? r0 : (NC - 1);
            int r1 = row0 + 16 + quad * 4 + i;   int rr1 = (r1 < NC) ? r1 : (NC - 1);
            int col = w * 64 + c * 16 + m;
            float e0 = us2f(*(const unsigned short*)(enh + (size_t)(c0 + rr0) * H + col));
            float e1 = us2f(*(const unsigned short*)(enh + (size_t)(c0 + rr1) * H + col));
            float v0 = acc0[c][i] + bv[c] + 0.1f * e0;
            float v1 = acc1[c][i] + bv[c] + 0.1f * e1;
            acc0[c][i] = v0; acc1[c][i] = v1;
            s0[i] += v0; q0[i] += v0 * v0;
            s1[i] += v1; q1[i] += v1 * v1;
        }
    }
    #pragma unroll
    for (int msk = 1; msk < 16; msk <<= 1) {
        #pragma unroll
        for (int i = 0; i < 4; ++i) {
            s0[i] += __shfl_xor(s0[i], msk); q0[i] += __shfl_xor(q0[i], msk);
            s1[i] += __shfl_xor(s1[i], msk); q1[i] += __shfl_xor(q1[i], msk);
        }
    }
    // cross-wave LN reduction: sred[w][rowlocal]
    __shared__ float sred[4][32];
    __shared__ float qred[4][32];
    if (m == 0) {
        #pragma unroll
        for (int i = 0; i < 4; ++i) {
            sred[w][quad * 4 + i] = s0[i];      qred[w][quad * 4 + i] = q0[i];
            sred[w][16 + quad * 4 + i] = s1[i]; qred[w][16 + quad * 4 + i] = q1[i];
        }
    }
    __syncthreads();
    float mu0[4], rs0[4], mu1[4], rs1[4];
    #pragma unroll
    for (int i = 0; i < 4; ++i) {
        int rl0 = quad * 4 + i, rl1 = 16 + quad * 4 + i;
        float S0 = sred[0][rl0] + sred[1][rl0] + sred[2][rl0] + sred[3][rl0];
        float Q0 = qred[0][rl0] + qred[1][rl0] + qred[2][rl0] + qred[3][rl0];
        float S1 = sred[0][rl1] + sred[1][rl1] + sred[2][rl1] + sred[3][rl1];
        float Q1 = qred[0][rl1] + qred[1][rl1] + qred[2][rl1] + qred[3][rl1];
        mu0[i] = S0 * (1.0f / H);
        rs0[i] = rsqrtf(Q0 * (1.0f / H) - mu0[i] * mu0[i] + LN_EPS);
        mu1[i] = S1 * (1.0f / H);
        rs1[i] = rsqrtf(Q1 * (1.0f / H) - mu1[i] * mu1[i] + LN_EPS);
    }
    #pragma unroll
    for (int c = 0; c < 4; ++c) {
        #pragma unroll
        for (int i = 0; i < 4; ++i) {
            int col = w * 64 + c * 16 + m;
            int r0 = row0 + quad * 4 + i;
            if (r0 < NC) {
                size_t idx = (size_t)(c0 + r0) * H + col;
                float y = (acc0[c][i] - mu0[i]) * rs0[i] * gv[c] + tv[c];
                float hn = us2f(*(const unsigned short*)(hbR + idx)) + fmaxf(y, 0.0f);
                hbW[idx] = __float2bfloat16(hn);
            }
            int r1 = row0 + 16 + quad * 4 + i;
            if (r1 < NC) {
                size_t idx = (size_t)(c0 + r1) * H + col;
                float y = (acc1[c][i] - mu1[i]) * rs1[i] * gv[c] + tv[c];
                float hn = us2f(*(const unsigned short*)(hbR + idx)) + fmaxf(y, 0.0f);
                hbW[idx] = __float2bfloat16(hn);
            }
        }
    }
}

// ===================== col-split input projection GEMM + fused LN/ReLU =====================
__global__ __launch_bounds__(256) void proj3_kernel(
    const bf16* __restrict__ xevb, const bf16* __restrict__ xiob,
    const bf16* __restrict__ wevT, const bf16* __restrict__ wioT,
    const float* __restrict__ bev, const float* __restrict__ gev, const float* __restrict__ betev,
    const float* __restrict__ bio, const float* __restrict__ gio, const float* __restrict__ betio,
    bf16* __restrict__ hbW) {
    int t = threadIdx.x, w = t >> 6, lane = t & 63;
    int quad = lane >> 4, m = lane & 15;
    int blk = blockIdx.x;
    const bf16 *X, *WT; const float *bb, *gg, *be;
    int K, node0, x0, nvalid;
    if (blk < NBEV32) {
        X = xevb; WT = wevT; K = D_EV; x0 = blk * 32; node0 = x0;
        bb = bev; gg = gev; be = betev;
        nvalid = (N_EVENT - x0 < 32) ? (N_EVENT - x0) : 32;
    } else {
        int b2 = blk - NBEV32;
        X = xiob; WT = wioT; K = D_IO; x0 = b2 * 32; node0 = N_EVENT + x0;
        bb = bio; gg = gio; be = betio;
        nvalid = 32;
    }
    f32x4 acc0[4], acc1[4];
    #pragma unroll
    for (int c = 0; c < 4; ++c) {
        acc0[c][0]=0.f; acc0[c][1]=0.f; acc0[c][2]=0.f; acc0[c][3]=0.f;
        acc1[c][0]=0.f; acc1[c][1]=0.f; acc1[c][2]=0.f; acc1[c][3]=0.f;
    }
    int rA0 = m;      if (rA0 >= nvalid) rA0 = nvalid - 1;
    int rA1 = 16 + m; if (rA1 >= nvalid) rA1 = nvalid - 1;
    const bf16* A0 = X + (size_t)(x0 + rA0) * K;
    const bf16* A1 = X + (size_t)(x0 + rA1) * K;
    const bf16* Bbase = WT + (size_t)(w * 64 + m) * K;

    for (int kc = 0; kc < K / 32; ++kc) {
        int k0 = kc * 32;
        bf16x8 a0 = *(const bf16x8*)(A0 + k0 + quad * 8);
        bf16x8 a1 = *(const bf16x8*)(A1 + k0 + quad * 8);
        const bf16* bp = Bbase + k0 + quad * 8;
        #pragma unroll
        for (int c = 0; c < 4; ++c) {
            bf16x8 b = *(const bf16x8*)(bp + (size_t)c * 16 * K);
            acc0[c] = __builtin_amdgcn_mfma_f32_16x16x32_bf16(a0, b, acc0[c], 0, 0, 0);
            acc1[c] = __builtin_amdgcn_mfma_f32_16x16x32_bf16(a1, b, acc1[c], 0, 0, 0);
        }
    }

    float bv[4], gv[4], tv[4];
    #pragma unroll
    for (int c = 0; c < 4; ++c) {
        int col = w * 64 + c * 16 + m;
        bv[c] = bb[col]; gv[c] = gg[col]; tv[c] = be[col];
    }
    float s0[4]={0,0,0,0}, q0[4]={0,0,0,0}, s1[4]={0,0,0,0}, q1[4]={0,0,0,0};
    #pragma unroll
    for (int c = 0; c < 4; ++c) {
        #pragma unroll
        for (int i = 0; i < 4; ++i) {
            float v0 = acc0[c][i] + bv[c];
            float v1 = acc1[c][i] + bv[c];
            acc0[c][i] = v0; acc1[c][i] = v1;
            s0[i] += v0; q0[i] += v0 * v0;
            s1[i] += v1; q1[i] += v1 * v1;
        }
    }
    #pragma unroll
    for (int msk = 1; msk < 16; msk <<= 1) {
        #pragma unroll
        for (int i = 0; i < 4; ++i) {
            s0[i] += __shfl_xor(s0[i], msk); q0[i] += __shfl_xor(q0[i], msk);
            s1[i] += __shfl_xor(s1[i], msk); q1[i] += __shfl_xor(q1[i], msk);
        }
    }
    __shared__ float sred[4][32];
    __shared__ float qred[4][32];
    if (m == 0) {
        #pragma unroll
        for (int i = 0; i < 4; ++i) {
            sred[w][quad * 4 + i] = s0[i];      qred[w][quad * 4 + i] = q0[i];
            sred[w][16 + quad * 4 + i] = s1[i]; qred[w][16 + quad * 4 + i] = q1[i];
        }
    }
    __syncthreads();
    float mu0[4], rs0[4], mu1[4], rs1[4];
    #pragma unroll
    for (int i = 0; i < 4; ++i) {
        int rl0 = quad * 4 + i, rl1 = 16 + quad * 4 + i;
        float S0 = sred[0][rl0] + sred[1][rl0] + sred[2][rl0] + sred[3][rl0];
        float Q0 = qred[0][rl0] + qred[1][rl0] + qred[2][rl0] + qred[3][rl0];
        float S1 = sred[0][rl1] + sred[1][rl1] + sred[2][rl1] + sred[3][rl1];
        float Q1 = qred[0][rl1] + qred[1][rl1] + qred[2][rl1] + qred[3][rl1];
        mu0[i] = S0 * (1.0f / H);
        rs0[i] = rsqrtf(Q0 * (1.0f / H) - mu0[i] * mu0[i] + LN_EPS);
        mu1[i] = S1 * (1.0f / H);
        rs1[i] = rsqrtf(Q1 * (1.0f / H) - mu1[i] * mu1[i] + LN_EPS);
    }
    #pragma unroll
    for (int c = 0; c < 4; ++c) {
        #pragma unroll
        for (int i = 0; i < 4; ++i) {
            int col = w * 64 + c * 16 + m;
            int r0 = quad * 4 + i;
            if (r0 < nvalid) {
                float y = (acc0[c][i] - mu0[i]) * rs0[i] * gv[c] + tv[c];
                hbW[(size_t)(node0 + r0) * H + col] = __float2bfloat16(fmaxf(y, 0.0f));
            }
            int r1 = 16 + quad * 4 + i;
            if (r1 < nvalid) {
                float y = (acc1[c][i] - mu1[i]) * rs1[i] * gv[c] + tv[c];
                hbW[(size_t)(node0 + r1) * H + col] = __float2bfloat16(fmaxf(y, 0.0f));
            }
        }
    }
}

__global__ __launch_bounds__(256) void out_kernel(const bf16* __restrict__ hb, float* __restrict__ out) {
    size_t i = (size_t)blockIdx.x * 256 + threadIdx.x;
    if (i < (size_t)N_EVENT * H) out[i] = us2f(*(const unsigned short*)(hb + i));
}

extern "C" void kernel_launch(void* const* d_in, const int* in_sizes, int n_in,
                              void* d_out, int out_size, void* d_ws, size_t ws_size,
                              hipStream_t stream) {
    const float* xev   = (const float*)d_in[0];
    const float* xio   = (const float*)d_in[1];
    const int*   ei    = (const int*)d_in[2];
    const int*   et    = (const int*)d_in[3];
    const float* ew    = (const float*)d_in[4];
    const float* wev   = (const float*)d_in[5];
    const float* bev   = (const float*)d_in[6];
    const float* gev   = (const float*)d_in[7];
    const float* betev = (const float*)d_in[8];
    const float* wio   = (const float*)d_in[9];
    const float* bio   = (const float*)d_in[10];
    const float* gio   = (const float*)d_in[11];
    const float* betio = (const float*)d_in[12];
    const float* emb   = (const float*)d_in[13];
    const float* mlp_w = (const float*)d_in[14];
    const float* mlp_b = (const float*)d_in[15];
    const float* bases = (const float*)d_in[16];
    const float* comp  = (const float*)d_in[17];
    const float* root  = (const float*)d_in[18];
    const float* bias  = (const float*)d_in[19];
    const float* gamma = (const float*)d_in[20];
    const float* beta  = (const float*)d_in[21];

    char* base = (char*)d_ws;
    size_t o = 0;
    auto alloc = [&](size_t bytes) { char* p = base + o; o = (o + bytes + 255) & ~(size_t)255; return p; };
    bf16*  hbA  = (bf16*) alloc((size_t)N_NODES * H * 2);          // 25.6 MB
    bf16*  hbB  = (bf16*) alloc((size_t)N_NODES * H * 2);          // 25.6 MB
    bf16*  enh  = (bf16*) alloc((size_t)N_NODES * H * 2);          // 25.6 MB
    char*  un   = alloc((size_t)NC * KPRE * 2);                    // 102.4 MB union
    bf16*  pre  = (bf16*)un;
    bf16*  xevb = (bf16*)un;
    bf16*  xiob = (bf16*)(un + (size_t)N_EVENT * D_EV * 2);
    bf16*  wevT = (bf16*) alloc((size_t)H * D_EV * 2);
    bf16*  wioT = (bf16*) alloc((size_t)H * D_IO * 2);
    bf16*  Bt3  = (bf16*) alloc((size_t)NLAYERS * H * KTOT * 2);   // 3.5 MB
    float* ctab = (float*)alloc(R * H * 4);
    float* wlast= (float*)alloc(H * 4);
    float* cinv = (float*)alloc((size_t)NKEY * 4);
    int*   bsum = (int*)  alloc(256 * 4);
    int*   cnt  = (int*)  alloc((size_t)NKEY * 4);
    int*   offs = (int*)  alloc((size_t)(NKEY + 4) * 4);
    int*   ssrc = (int*)  alloc((size_t)E_EDGES * 4);
    float* sew  = (float*)alloc((size_t)E_EDGES * 4);
    // ~195 MB total

    hipMemsetAsync(cnt, 0, (size_t)NKEY * sizeof(int), stream);

    // edge presort
    hist_kernel<<<(E_EDGES + 255) / 256, 256, 0, stream>>>(ei, et, cnt);
    scan1_kernel<<<NCHUNK, 256, 0, stream>>>(cnt, offs, bsum);
    scan2_kernel<<<1, 256, 0, stream>>>(bsum);
    scan3_kernel<<<(NKEY + 255) / 256, 256, 0, stream>>>(offs, bsum);
    cinv_kernel<<<(NKEY + 255) / 256, 256, 0, stream>>>(cnt, cinv);
    sort_kernel<<<(E_EDGES + 255) / 256, 256, 0, stream>>>(ei, et, ew, offs, cnt, ssrc, sew);

    // dtype prep
    cvt_x_kernel<<<12500, 256, 0, stream>>>(xev, xio, xevb, xiob);
    cvt_w_kernel<<<H, 256, 0, stream>>>(wev, wio, wevT, wioT);
    build_Bt_kernel<<<NLAYERS * KTOT, 256, 0, stream>>>(bases, comp, root, Bt3);

    // node features + edge-feature means
    proj3_kernel<<<NBEV32 + NBIO32, 256, 0, stream>>>(
        xevb, xiob, wevT, wioT, bev, gev, betev, bio, gio, betio, hbA);
    edge_table_kernel<<<R, 256, 0, stream>>>(emb, mlp_w, mlp_b, ctab, wlast);
    enh_bucket_kernel<<<N_NODES / 4, 256, 0, stream>>>(offs, sew, ctab, wlast, enh);

    for (int l = 0; l < NLAYERS; ++l) {
        bf16* hbR = (l & 1) ? hbB : hbA;
        bf16* hbW = (l & 1) ? hbA : hbB;
        const bf16* Bt = Bt3 + (size_t)l * H * KTOT;
        for (int c = 0; c < NCHUNKS; ++c) {
            int c0 = c * NC;
            bucket_msg_kernel<<<NC, 256, 0, stream>>>(offs, ssrc, hbR, cinv, pre, c0);
            gemm3_kernel<<<(NC + 31) / 32, 256, 0, stream>>>(
                pre, hbR, Bt, enh, bias + l * H, gamma + l * H, beta + l * H, hbW, c0);
        }
    }

    out_kernel<<<((size_t)N_EVENT * H + 255) / 256, 256, 0, stream>>>(hbB, (float*)d_out);
}